// Round 10
// baseline (107.050 us; speedup 1.0000x reference)
//
#include <hip/hip_runtime.h>

// Problem constants (B,C,H,W = 2,64,48,48; nh=8 -> d=8, L=2304)
#define LL   2304
#define CCH  64
#define NHD  8

static constexpr float QSCALE = 0.35355339059327373f;  // 8^-0.5
static constexpr float LOG2E  = 1.4426950408889634f;

typedef _Float16 half2_t  __attribute__((ext_vector_type(2)));
typedef _Float16 half4_t  __attribute__((ext_vector_type(4)));
typedef _Float16 half8_t  __attribute__((ext_vector_type(8)));
typedef float    float16_t __attribute__((ext_vector_type(16)));

__device__ __forceinline__ half2_t pk_f16(float a, float b) {
    return __builtin_bit_cast(half2_t, __builtin_amdgcn_cvt_pkrtz(a, b));
}

// v_mfma_f32_32x32x8_f16 lane maps (K=8):
//   A[m = lane&31][k = (lane>>5)*4 + j]   (half4 per lane)
//   B[k = (lane>>5)*4 + j][n = lane&31]
//   C/D: col = lane&31, row = (reg&3) + 8*(reg>>2) + 4*(lane>>5)

// ---------------------------------------------------------------------------
// Kernel 1: q/k/v = conv1x1(x, W*, b*)  (verified R7-R9).  mat==0 blocks also
// initialize out to bo (atomic accumulation target for k_av_out).
// grid (72 ltiles of 32, B, 3 mats), block 256 = 32 l x 8 heads.
// ---------------------------------------------------------------------------
__global__ __launch_bounds__(256) void k_qkv(
    const float* __restrict__ x,
    const float* __restrict__ Wq, const float* __restrict__ bq,
    const float* __restrict__ Wk, const float* __restrict__ bk,
    const float* __restrict__ Wv, const float* __restrict__ bv,
    const float* __restrict__ bo,
    float* __restrict__ qout, float* __restrict__ outp,
    _Float16* __restrict__ Qt, _Float16* __restrict__ Kt, _Float16* __restrict__ Vt)
{
    __shared__ float xs[64][32];
    __shared__ float wsm[64][64];
    const int t   = threadIdx.x;
    const int l0  = blockIdx.x * 32;
    const int b   = blockIdx.y;
    const int mat = blockIdx.z;
    const float* W    = (mat == 0) ? Wq : (mat == 1 ? Wk : Wv);
    const float* bias = (mat == 0) ? bq : (mat == 1 ? bk : bv);
    const float* xb = x + (long)b * CCH * LL;

    if (mat == 0) {
        #pragma unroll
        for (int p = 0; p < 2; ++p) {
            int flat = (p * 256 + t) * 4;       // 2048 floats = 64co x 32l
            int co = flat >> 5, l = flat & 31;
            float bv4 = bo[co];
            float4 vv = make_float4(bv4, bv4, bv4, bv4);
            *(float4*)&outp[((long)b * CCH + co) * LL + l0 + l] = vv;
        }
    }

    #pragma unroll
    for (int p = 0; p < 2; ++p) {
        int flat = (p * 256 + t) * 4;
        int c = flat >> 5, l = flat & 31;
        *(float4*)&xs[c][l] = *(const float4*)&xb[(long)c * LL + l0 + l];
    }
    #pragma unroll
    for (int p = 0; p < 4; ++p) {
        int flat = (p * 256 + t) * 4;
        int c = flat >> 6, l = flat & 63;
        *(float4*)&wsm[c][l] = *(const float4*)&W[flat];
    }
    __syncthreads();   // xs/wsm are cross-wave: barrier required here

    const int l  = t & 31;
    const int cg = t >> 5;  // head 0..7
    float acc[8];
    #pragma unroll
    for (int j = 0; j < 8; ++j) acc[j] = 0.f;
    for (int cp = 0; cp < 64; ++cp) {
        float xv = xs[cp][l];
        #pragma unroll
        for (int j = 0; j < 8; ++j) acc[j] = fmaf(wsm[cg * 8 + j][cp], xv, acc[j]);
    }
    long row = (long)(b * NHD + cg) * LL + l0 + l;   // [bh][l] row, 8 f16 each
    if (mat == 0) {
        half8_t pq;
        #pragma unroll
        for (int j = 0; j < 8; ++j) {
            float qv = (acc[j] + bias[cg * 8 + j]) * QSCALE;
            qout[((long)b * CCH + cg * 8 + j) * LL + l0 + l] = qv;
            pq[j] = (_Float16)(qv * LOG2E);
        }
        *(half8_t*)(Qt + row * 8) = pq;
    } else if (mat == 1) {
        half8_t pk;
        #pragma unroll
        for (int j = 0; j < 8; ++j) pk[j] = (_Float16)(acc[j] + bias[cg * 8 + j]);
        *(half8_t*)(Kt + row * 8) = pk;
    } else {
        half8_t pv;
        #pragma unroll
        for (int j = 0; j < 8; ++j) pv[j] = (_Float16)(acc[j] + bias[cg * 8 + j]);
        *(half8_t*)(Vt + row * 8) = pv;
    }
}

// ---------------------------------------------------------------------------
// Kernel 2: D[k] = sum_q 2^(Q'[q].K[k]); V2[bh][c][k] = V[k][c]*256/D[k].
// BARRIER-FREE main loop: thread t stages lQ row t; wave w reads exactly rows
// 64w..64w+63 (its own threads' rows) -> staging is wave-local, same-wave
// ds_write->ds_read ordering is guaranteed by lgkmcnt waits.  Only the
// cross-wave Dp/rDs reduction keeps barriers.
// grid (72 ktiles of 32, 16 bh), block 256 = 4 waves splitting q.
// ---------------------------------------------------------------------------
__global__ __launch_bounds__(256) void k_denom(
    const _Float16* __restrict__ Qt, const _Float16* __restrict__ Kt,
    const _Float16* __restrict__ Vt, _Float16* __restrict__ V2)
{
    __shared__ _Float16 lQ[2][256][4];   // 4KB: d-half-split Q chunk (256 rows)
    __shared__ float Dp[4][32];
    __shared__ float rDs[32];
    const int t    = threadIdx.x;
    const int bh   = blockIdx.y;
    const int k0   = blockIdx.x * 32;
    const int lane = t & 63, w = t >> 6;
    const int half = lane >> 5, l31 = lane & 31;

    half4_t kA = *(const half4_t*)(Kt + ((long)bh * LL + k0 + l31) * 8 + half * 4);

    const float4* qbase = (const float4*)(Qt + (long)bh * LL * 8);  // 16B rows
    float4 pre = qbase[t];

    float16_t Dacc = {};
    for (int ch = 0; ch < 9; ++ch) {
        *(float2*)&lQ[0][t][0] = make_float2(pre.x, pre.y);   // d 0..3
        *(float2*)&lQ[1][t][0] = make_float2(pre.z, pre.w);   // d 4..7
        if (ch + 1 < 9) pre = qbase[(ch + 1) * 256 + t];
        #pragma unroll
        for (int T = 0; T < 2; ++T) {
            half4_t qB = *(const half4_t*)&lQ[half][(2 * w + T) * 32 + l31][0];
            float16_t S = __builtin_amdgcn_mfma_f32_32x32x8f16(kA, qB, (float16_t){}, 0, 0, 0);
            #pragma unroll
            for (int r = 0; r < 16; ++r) Dacc[r] += __builtin_amdgcn_exp2f(S[r]);
        }
    }
    #pragma unroll
    for (int r = 0; r < 16; ++r) {
        float v = Dacc[r];
        v += __shfl_xor(v, 1);  v += __shfl_xor(v, 2);  v += __shfl_xor(v, 4);
        v += __shfl_xor(v, 8);  v += __shfl_xor(v, 16);
        Dacc[r] = v;
    }
    if (l31 == 0) {
        #pragma unroll
        for (int r = 0; r < 16; ++r) {
            int row = (r & 3) + 8 * (r >> 2) + 4 * half;
            Dp[w][row] = Dacc[r];
        }
    }
    __syncthreads();   // cross-wave: Dp
    if (t < 32) rDs[t] = 256.0f / (Dp[0][t] + Dp[1][t] + Dp[2][t] + Dp[3][t]);
    __syncthreads();   // cross-wave: rDs
    {   // V2[bh][c][k0+kk] = V[k0+kk][c] * rDs[kk]
        int kk = t >> 3, c = t & 7;
        float v = (float)Vt[((long)bh * LL + k0 + kk) * 8 + c];
        V2[((long)bh * 8 + c) * LL + k0 + kk] = (_Float16)(v * rDs[kk]);
    }
}

// ---------------------------------------------------------------------------
// Kernel 3 (AV + Wo, occupancy-preserving, verified R9): block = (32-q tile,
// bh); the 4 waves are the 4 k-splits of 576.  BARRIER-FREE main loop: the
// staging map has sw = t>>6 = w, so wave w writes lK[w]/lV[w] and reads only
// lK[w]/lV[w] -> wave-local, no cross-wave hazard.  Cross-wave barriers
// remain only around the Osp/WoS epilogue.
// 8 producers per out element via atomicAdd onto bo-initialized out.
// grid (72, 16), block 256.
// ---------------------------------------------------------------------------
__global__ __launch_bounds__(256, 4) void k_av_out(
    const _Float16* __restrict__ Qt, const _Float16* __restrict__ Kt,
    const _Float16* __restrict__ V2, const float* __restrict__ Wo,
    float* __restrict__ out)
{
    __shared__ _Float16 lK[4][2][64][4];   // 4KB: per-wave d-half-split K seg
    __shared__ _Float16 lV[4][8][72];      // 4.5KB: per-wave V2 seg (pad +8)
    __shared__ float    WoS[64][9];        // 2.25KB: WoS[co][c] = Wo[co][h*8+c]
    __shared__ float    Osp[4][8][33];     // 4.2KB: wave partials (pad +1)
    const int t    = threadIdx.x;
    const int qb   = blockIdx.x;           // 0..71: q-tile of 32
    const int bh   = blockIdx.y;           // 0..15
    const int b = bh >> 3, h = bh & 7;
    const int lane = t & 63, w = t >> 6;   // wave w owns k in [576w, 576w+576)
    const int half = lane >> 5, l31 = lane & 31;
    const int cl   = l31 & 7;

    // stage Wo slice for this head: 512 floats, h*8 offset is 32B-aligned
    if (t < 128) {
        int co = t >> 1, c4 = (t & 1) * 4;
        float4 v = *(const float4*)&Wo[co * 64 + h * 8 + c4];
        WoS[co][c4 + 0] = v.x; WoS[co][c4 + 1] = v.y;
        WoS[co][c4 + 2] = v.z; WoS[co][c4 + 3] = v.w;
    }

    // fixed B operand: this block's 32 q-cols (same for all 4 waves)
    half4_t qB = *(const half4_t*)(Qt + ((long)bh * LL + qb * 32 + l31) * 8 + half * 4);

    // staging map: thread t loads for wave seg sw = t>>6 == its own wave
    const int sw = t >> 6, sr = t & 63;            // K row within seg
    const int vc = (t & 63) >> 3, vj = t & 7;      // V2: c row, j8 group
    const _Float16* kbg = Kt + ((long)bh * LL + 576 * sw) * 8;
    const _Float16* vbg = V2 + ((long)bh * 8 + vc) * LL + 576 * sw + vj * 8;

    float4 preK = *(const float4*)(kbg + (long)sr * 8);
    float4 preV = *(const float4*)(vbg);

    float16_t O = {};
    for (int it = 0; it < 9; ++it) {       // 9 x 64k per wave, no barriers
        *(float2*)&lK[sw][0][sr][0] = make_float2(preK.x, preK.y);   // d 0..3
        *(float2*)&lK[sw][1][sr][0] = make_float2(preK.z, preK.w);   // d 4..7
        *(float4*)&lV[sw][vc][vj * 8] = preV;
        if (it + 1 < 9) {
            preK = *(const float4*)(kbg + (long)(64 * (it + 1) + sr) * 8);
            preV = *(const float4*)(vbg + 64 * (it + 1));
        }
        #pragma unroll
        for (int T = 0; T < 2; ++T) {
            const int kb = T * 32;
            half4_t kA = *(const half4_t*)&lK[w][half][kb + l31][0];
            float16_t S = __builtin_amdgcn_mfma_f32_32x32x8f16(kA, qB, (float16_t){}, 0, 0, 0);
            #pragma unroll
            for (int g = 0; g < 4; ++g) {
                half2_t p0 = pk_f16(__builtin_amdgcn_exp2f(S[4 * g + 0]),
                                    __builtin_amdgcn_exp2f(S[4 * g + 1]));
                half2_t p1 = pk_f16(__builtin_amdgcn_exp2f(S[4 * g + 2]),
                                    __builtin_amdgcn_exp2f(S[4 * g + 3]));
                half4_t pB = __builtin_shufflevector(p0, p1, 0, 1, 2, 3);
                half4_t vA = *(const half4_t*)&lV[w][cl][kb + g * 8 + half * 4];
                O = __builtin_amdgcn_mfma_f32_32x32x8f16(vA, pB, O, 0, 0, 0);
            }
        }
    }

    // wave partials: rows c = r + 4*half (c<8 in regs 0..3), col q = l31
    #pragma unroll
    for (int r = 0; r < 4; ++r)
        Osp[w][r + 4 * half][l31] = O[r] * (1.0f / 256.0f);
    __syncthreads();   // cross-wave: Osp complete (also covers WoS staging)

    // epilogue: thread = (q = t&31, cog = t>>5); sum k-split partials, apply
    // Wo slice (broadcast reads), 8 coalesced atomics (2x128B segs per instr)
    {
        const int q = t & 31, cog = t >> 5;
        float o8[8];
        #pragma unroll
        for (int c = 0; c < 8; ++c)
            o8[c] = Osp[0][c][q] + Osp[1][c][q] + Osp[2][c][q] + Osp[3][c][q];
        float* ob = out + ((long)b * CCH + cog * 8) * LL + qb * 32 + q;
        #pragma unroll
        for (int j = 0; j < 8; ++j) {
            float a = 0.f;
            #pragma unroll
            for (int c = 0; c < 8; ++c)
                a = fmaf(WoS[cog * 8 + j][c], o8[c], a);
            atomicAdd(ob + (long)j * LL, a);
        }
    }
}

// ---------------------------------------------------------------------------
extern "C" void kernel_launch(void* const* d_in, const int* in_sizes, int n_in,
                              void* d_out, int out_size, void* d_ws, size_t ws_size,
                              hipStream_t stream)
{
    const float* x  = (const float*)d_in[0];
    const float* Wq = (const float*)d_in[1];
    const float* bq = (const float*)d_in[2];
    const float* Wk = (const float*)d_in[3];
    const float* bk = (const float*)d_in[4];
    const float* Wv = (const float*)d_in[5];
    const float* bv = (const float*)d_in[6];
    const float* Wo = (const float*)d_in[7];
    const float* bo = (const float*)d_in[8];

    float* out  = (float*)d_out;          // [2][64][2304]
    float* qout = out + 294912;           // second tuple output: scaled q

    // ws: 4 f16 buffers (576KB ea) = 2.25 MB
    _Float16* Qt = (_Float16*)d_ws;       // [16][2304][8] f16, * log2e*d^-0.5
    _Float16* Kt = Qt + 294912;           // [16][2304][8] f16
    _Float16* Vt = Kt + 294912;           // [16][2304][8] f16 (raw V)
    _Float16* V2 = Vt + 294912;           // [16][8][2304] f16 = V^T * 256/D

    k_qkv   <<<dim3(72, 2, 3), 256, 0, stream>>>(x, Wq, bq, Wk, bk, Wv, bv, bo,
                                                 qout, out, Qt, Kt, Vt);
    k_denom <<<dim3(72, 16),   256, 0, stream>>>(Qt, Kt, Vt, V2);
    k_av_out<<<dim3(72, 16),   256, 0, stream>>>(Qt, Kt, V2, Wo, out);
}